// Round 9
// baseline (930.006 us; speedup 1.0000x reference)
//
#include <hip/hip_runtime.h>
#include <hip/hip_cooperative_groups.h>
#include <hip/hip_fp16.h>
#include <math.h>

namespace cg = cooperative_groups;

// SSL compressor gain: 128 independent nonlinear 2-state IIR chains, T=131072.
// Round 9: ONE cooperative kernel. r8 evidence: total kernel work ~120us but
// 10 dispatches cost 357us -> ~20-25us fixed overhead per graph node. All
// phases fused with grid.sync(): decimated map -> compose0 -> 3x(jac ->
// affine compose) -> out. Newton iterations are now ~7us each (not ~2
// dispatch overheads), so keep 3 (r8-proven absmax floor 0.0625).

constexpr int   T_LEN    = 131072;
constexpr int   NCM      = 64;              // coarse map chunks
constexpr int   CM       = T_LEN / NCM;     // 2048 samples
constexpr int   SUB      = 8;               // snapshots per map chunk (every 256)
constexpr int   NC       = NCM * SUB;       // 512 fine chunks
constexpr int   CF       = T_LEN / NC;      // 256 samples
constexpr int   K        = 16;              // ES nodes: 0 .. -8, h=8/15
constexpr float STEP_ES  = 8.0f / 15.0f;
constexpr float INV_STEP = 15.0f / 8.0f;
constexpr int   DPF      = 8;               // float4 prefetch depth
constexpr int   NV_ROW   = T_LEN >> 2;
constexpr int   NIT      = 3;               // Newton iterations

struct SslP { float nhs, hst, nq, r, a_af, a_as, a_sf, a_ss,
                    d_af, d_as, d_sf, d_ss, nhs_h; };

__device__ __forceinline__ SslP ssl_params(
        const float* cth, const float* rl, const float* fbl,
        const float* uaf, const float* uas, const float* usf, const float* uss)
{
    const double FS = 44100.0;
    const double T_AF_MIN = 820.0 * 4.7e-07 * 0.8,   T_AF_MAX = 270000.0 * 4.7e-07 * 1.2;
    const double T_AS_MIN = 820.0 * 6.8e-06 * 0.8,   T_AS_MAX = 270000.0 * 6.8e-06 * 100.0;
    const double T_SF_MIN = 91000.0 * 4.7e-07 * 0.8, T_SF_MAX = 1200000.0 * 4.7e-07 * 1.2;
    const double T_SS_MIN = 750000.0 * 6.8e-06 * 0.8, T_SS_MAX = 750000.0 * 6.8e-06 * 100.0;

    double cr    = fmax(exp((double)rl[0]) + 1.0, 1.0 + 1e-4);
    double fb    = 1.0 / (1.0 + exp(-(double)fbl[0]));
    double slope = 1.0 - 1.0 / cr;

    double s_af = T_AF_MIN + (T_AF_MAX - T_AF_MIN) / (1.0 + exp(-(double)uaf[0]));
    double s_as = T_AS_MIN + (T_AS_MAX - T_AS_MIN) / (1.0 + exp(-(double)uas[0]));
    double s_sf = T_SF_MIN + (T_SF_MAX - T_SF_MIN) / (1.0 + exp(-(double)usf[0]));
    double s_ss = T_SS_MIN + (T_SS_MAX - T_SS_MIN) / (1.0 + exp(-(double)uss[0]));

    SslP p;
    p.a_af = (float)exp(-1.0 / (FS * s_af));
    p.a_as = (float)exp(-1.0 / (FS * s_as));
    p.a_sf = (float)exp(-1.0 / (FS * s_sf));
    p.a_ss = (float)exp(-1.0 / (FS * s_ss));
    double q = 0.5 * slope * fb;
    p.nq    = (float)(-q);
    p.r     = (float)(0.5 + q);
    p.nhs   = (float)(-0.5 * slope);
    p.hst   = (float)(0.5 * slope * (double)cth[0]);
    p.d_af  = p.a_af * p.a_af;  p.d_as = p.a_as * p.a_as;   // 2x-decimated coefs
    p.d_sf  = p.a_sf * p.a_sf;  p.d_ss = p.a_ss * p.a_ss;
    p.nhs_h = (float)(-0.25 * slope);                       // pair-avg input coef
    return p;
}

__global__ __launch_bounds__(256, 2) void ssl_fused(
        const float* __restrict__ x, float* __restrict__ out,
        __half2* __restrict__ mp, float2* __restrict__ bnd,
        float4* __restrict__ Jv, float2* __restrict__ gv,
        const float* cth, const float* rl, const float* fbl,
        const float* uaf, const float* uas, const float* usf, const float* uss,
        int B)
{
    cg::grid_group grid = cg::this_grid();
    const int tid = blockIdx.x * 256 + threadIdx.x;
    const SslP P = ssl_params(cth, rl, fbl, uaf, uas, usf, uss);

    // ---------------- Phase M: decimated diagonal chunk maps ----------------
    // tid = bc*K + k; each float4 = 2 decimated steps (pair-avg x, squared a).
    {
        int k  = tid & (K - 1);
        int bc = tid >> 4;                   // b*NCM + c
        if (bc < B * NCM) {
            int c = bc & (NCM - 1);
            int b = bc >> 6;                 // NCM = 64
            const float nhs_h = P.nhs_h, hst = P.hst, nq = P.nq, r = P.r;
            const float d_af = P.d_af, d_as = P.d_as, d_sf = P.d_sf, d_ss = P.d_ss;
            float v0s = -STEP_ES * (float)k;
            float EF = v0s, ES = v0s, Y = EF + ES;
            const float4* __restrict__ xr = reinterpret_cast<const float4*>(x + (size_t)b * T_LEN);
            const int v0 = c * (CM >> 2);

            float4 buf[DPF];
            #pragma unroll
            for (int i = 0; i < DPF; ++i) buf[i] = xr[v0 + i];

            #pragma unroll 1
            for (int q8 = 0; q8 < SUB; ++q8) {
                const int s0 = v0 + q8 * (CF >> 2);
                for (int v = s0; v < s0 + (CF >> 2); v += DPF) {
                    #pragma unroll
                    for (int i = 0; i < DPF; ++i) {
                        float4 xv = buf[i];
                        int nxt = v + DPF + i;
                        if (nxt < NV_ROW) buf[i] = xr[nxt];
#define DEC_STEP(X0, X1) { \
                        float sx2 = fmaf(nhs_h, (X0), fmaf(nhs_h, (X1), hst)); \
                        float u2  = fmaf(nq, Y, sx2); \
                        float t2  = fminf(u2, 0.0f); \
                        bool att  = sx2 < r * Y; \
                        float af  = att ? d_af : d_sf; \
                        float as2 = att ? d_as : d_ss; \
                        EF = fmaf(af,  EF - t2, t2); \
                        ES = fmaf(as2, ES - t2, t2); \
                        Y  = EF + ES; }
                        DEC_STEP(xv.x, xv.y)
                        DEC_STEP(xv.z, xv.w)
#undef DEC_STEP
                    }
                }
                mp[((size_t)bc * SUB + q8) * K + k] = __floats2half2_rn(EF, ES);
            }
        }
    }
    grid.sync();

    // ---------------- Phase C0: serial interp compose -> guesses ----------------
    if (tid < B) {
        int b = tid;
        float EF = 0.0f, ES = 0.0f;
        for (int c = 0; c < NCM; ++c) {
            int bc = b * NCM + c;
            bnd[b * NC + SUB * c] = make_float2(EF, ES);
            float t = -ES * INV_STEP;
            int idx = (int)t;
            idx = idx < 0 ? 0 : (idx > K - 2 ? K - 2 : idx);
            float u = t - (float)idx;
            const __half2* m = &mp[(size_t)bc * SUB * K];
            #pragma unroll
            for (int q = 0; q < SUB; ++q) {
                float2 a0 = __half22float2(m[q * K + idx]);
                float2 a1 = __half22float2(m[q * K + idx + 1]);
                float gx = a0.x + (a1.x - a0.x) * u;
                float gy = a0.y + (a1.y - a0.y) * u;
                if (q < SUB - 1) bnd[b * NC + SUB * c + 1 + q] = make_float2(gx, gy);
                else { EF = gx; ES = gy; }
            }
        }
    }
    grid.sync();

    // ---------------- Newton iterations: jac -> affine compose ----------------
    #pragma unroll 1
    for (int it = 0; it < NIT; ++it) {
        if (tid < B * NC) {
            int b = tid & 127;               // B = 128
            int c = tid >> 7;
            const float nhs = P.nhs, hst = P.hst, nq = P.nq, r = P.r;
            const float a_af = P.a_af, a_as = P.a_as, a_sf = P.a_sf, a_ss = P.a_ss;

            float2 s0 = bnd[b * NC + c];
            float EF = s0.x, ES = s0.y, Y = EF + ES;
            float jFx = 1.0f, jFy = 0.0f, jSx = 0.0f, jSy = 1.0f;

            const float4* __restrict__ xr = reinterpret_cast<const float4*>(x + (size_t)b * T_LEN);
            const int v0 = c * (CF >> 2), v1 = v0 + (CF >> 2);

            float4 buf[DPF];
            #pragma unroll
            for (int i = 0; i < DPF; ++i) buf[i] = xr[v0 + i];

            for (int v = v0; v < v1; v += DPF) {
                #pragma unroll
                for (int i = 0; i < DPF; ++i) {
                    float4 xv = buf[i];
                    int nxt = v + DPF + i;
                    if (nxt < NV_ROW) buf[i] = xr[nxt];
#define SSL_STEP_J(XV) { \
                    float sx2 = fmaf(nhs, (XV), hst); \
                    float u2  = fmaf(nq, Y, sx2); \
                    float t2  = fminf(u2, 0.0f); \
                    bool g2   = u2 < 0.0f; \
                    bool att  = sx2 < r * Y; \
                    float af  = att ? a_af : a_sf; \
                    float as2 = att ? a_as : a_ss; \
                    float jYx = jFx + jSx, jYy = jFy + jSy; \
                    float jtx = g2 ? nq * jYx : 0.0f; \
                    float jty = g2 ? nq * jYy : 0.0f; \
                    jFx = fmaf(af,  jFx - jtx, jtx); \
                    jFy = fmaf(af,  jFy - jty, jty); \
                    jSx = fmaf(as2, jSx - jtx, jtx); \
                    jSy = fmaf(as2, jSy - jty, jty); \
                    EF  = fmaf(af,  EF - t2, t2); \
                    ES  = fmaf(as2, ES - t2, t2); \
                    Y   = EF + ES; }
                    SSL_STEP_J(xv.x)
                    SSL_STEP_J(xv.y)
                    SSL_STEP_J(xv.z)
                    SSL_STEP_J(xv.w)
#undef SSL_STEP_J
                }
            }
            Jv[b * NC + c] = make_float4(jFx, jFy, jSx, jSy);
            gv[b * NC + c] = make_float2(EF - (jFx * s0.x + jFy * s0.y),
                                         ES - (jSx * s0.x + jSy * s0.y));
        }
        grid.sync();

        if (tid < B) {
            const float4* Jr = Jv + (size_t)tid * NC;
            const float2* gr = gv + (size_t)tid * NC;
            float2* br = bnd + (size_t)tid * NC;
            float sx = 0.0f, sy = 0.0f;
            #pragma unroll 8
            for (int c = 0; c < NC; ++c) {
                br[c] = make_float2(sx, sy);
                float4 J = Jr[c];
                float2 g = gr[c];
                float nx = g.x + J.x * sx + J.y * sy;
                float ny = g.y + J.z * sx + J.w * sy;
                sx = nx; sy = ny;
            }
        }
        grid.sync();
    }

    // ---------------- Phase OUT: rerun fine chunks, store y ----------------
    if (tid < B * NC) {
        int b = tid & 127;
        int c = tid >> 7;
        const float nhs = P.nhs, hst = P.hst, nq = P.nq, r = P.r;
        const float a_af = P.a_af, a_as = P.a_as, a_sf = P.a_sf, a_ss = P.a_ss;

        float2 s = bnd[b * NC + c];
        float EF = s.x, ES = s.y, Y = EF + ES;
        const float4* __restrict__ xr = reinterpret_cast<const float4*>(x + (size_t)b * T_LEN);
        float4* __restrict__ yr       = reinterpret_cast<float4*>(out + (size_t)b * T_LEN);
        const int v0 = c * (CF >> 2), v1 = v0 + (CF >> 2);

        float4 buf[DPF];
        #pragma unroll
        for (int i = 0; i < DPF; ++i) buf[i] = xr[v0 + i];

        for (int v = v0; v < v1; v += DPF) {
            #pragma unroll
            for (int i = 0; i < DPF; ++i) {
                float4 xv = buf[i];
                int nxt = v + DPF + i;
                if (nxt < NV_ROW) buf[i] = xr[nxt];
                float4 yo;
#define SSL_STEP(XV, YOUT) { \
                float sx2 = fmaf(nhs, (XV), hst); \
                float u2  = fmaf(nq, Y, sx2); \
                float t2  = fminf(u2, 0.0f); \
                bool att  = sx2 < r * Y; \
                float af  = att ? a_af : a_sf; \
                float as2 = att ? a_as : a_ss; \
                EF = fmaf(af,  EF - t2, t2); \
                ES = fmaf(as2, ES - t2, t2); \
                Y  = EF + ES; \
                (YOUT) = Y; }
                SSL_STEP(xv.x, yo.x)
                SSL_STEP(xv.y, yo.y)
                SSL_STEP(xv.z, yo.z)
                SSL_STEP(xv.w, yo.w)
#undef SSL_STEP
                yr[v + i] = yo;
            }
        }
    }
}

extern "C" void kernel_launch(void* const* d_in, const int* in_sizes, int n_in,
                              void* d_out, int out_size, void* d_ws, size_t ws_size,
                              hipStream_t stream) {
    const float* x = (const float*)d_in[0];
    float* outp = (float*)d_out;
    int B = in_sizes[0] / T_LEN;         // 128
    const size_t NCt = (size_t)B * NC;   // 65536

    // ws layout (16B-aligned first): Jv 1MB | mp 4MB | bnd 0.5MB | gv 0.5MB
    float4*  Jv  = (float4*)d_ws;
    __half2* mp  = (__half2*)(Jv + NCt);
    float2*  bnd = (float2*)(mp + (size_t)B * NCM * SUB * K);
    float2*  gv  = bnd + NCt;

    const float* cth = (const float*)d_in[1];
    const float* rl  = (const float*)d_in[2];
    const float* fbl = (const float*)d_in[3];
    const float* uaf = (const float*)d_in[4];
    const float* uas = (const float*)d_in[5];
    const float* usf = (const float*)d_in[6];
    const float* uss = (const float*)d_in[7];

    int nthreads = B * NCM * K;          // 131072
    int nblocks  = (nthreads + 255) / 256;  // 512 = 2 WG/CU (launch_bounds)

    void* kargs[] = { (void*)&x, (void*)&outp, (void*)&mp, (void*)&bnd,
                      (void*)&Jv, (void*)&gv,
                      (void*)&cth, (void*)&rl, (void*)&fbl,
                      (void*)&uaf, (void*)&uas, (void*)&usf, (void*)&uss,
                      (void*)&B };
    hipLaunchCooperativeKernel((void*)ssl_fused, dim3(nblocks), dim3(256),
                               kargs, 0, stream);
}

// Round 11
// 205.956 us; speedup vs baseline: 4.5156x; 4.5156x over previous
//
#include <hip/hip_runtime.h>
#include <hip/hip_fp16.h>
#include <math.h>

// SSL compressor gain: 128 independent nonlinear 2-state IIR chains, T=131072.
// Round 11: round-10 structure with the LDS staging bug fixed.
//   r10 NaN post-mortem: staging loop copied (MP_ROW>>3)/512 = 2 x 512 float4
//   = 16KB, but the table is MP_ROW/4 = 2048 float4 = 32KB (half2=4B,
//   float4=16B -> /4 not /8). Coarse chunks 32..63 read uninitialized LDS ->
//   garbage states -> overflow -> NaN. Fix: index-robust copy loop.
// Structure (r10): map (r8-proven decimated, 67us) -> ssl_row per-row block:
//   stage map table in LDS -> serial compose0 on LDS -> 3x (jac 1chunk/thread
//   -> Hillis-Steele affine scan in LDS) -> out. No grid-wide sync anywhere.

constexpr int   T_LEN    = 131072;
constexpr int   NCM      = 64;              // coarse map chunks
constexpr int   CM       = T_LEN / NCM;     // 2048 samples
constexpr int   SUB      = 8;               // snapshots per map chunk (every 256)
constexpr int   NC       = NCM * SUB;       // 512 fine chunks
constexpr int   CF       = T_LEN / NC;      // 256 samples
constexpr int   K        = 16;              // ES nodes: 0 .. -8, h=8/15
constexpr float STEP_ES  = 8.0f / 15.0f;
constexpr float INV_STEP = 15.0f / 8.0f;
constexpr int   DPF      = 8;               // float4 prefetch depth
constexpr int   NV_ROW   = T_LEN >> 2;
constexpr int   NIT      = 3;               // Newton iterations
constexpr int   MP_ROW   = NCM * SUB * K;   // 8192 half2 per row (32 KB)

// pw: 0 nhs, 1 hst, 2 nq, 3 r, 4..7 a_{af,as,sf,ss}, 8..11 squared (2x-decim),
//     12 nhs_h
__global__ void ssl_params_k(
        float* __restrict__ pw,
        const float* cth, const float* rl, const float* fbl,
        const float* uaf, const float* uas, const float* usf, const float* uss)
{
    const double FS = 44100.0;
    const double T_AF_MIN = 820.0 * 4.7e-07 * 0.8,   T_AF_MAX = 270000.0 * 4.7e-07 * 1.2;
    const double T_AS_MIN = 820.0 * 6.8e-06 * 0.8,   T_AS_MAX = 270000.0 * 6.8e-06 * 100.0;
    const double T_SF_MIN = 91000.0 * 4.7e-07 * 0.8, T_SF_MAX = 1200000.0 * 4.7e-07 * 1.2;
    const double T_SS_MIN = 750000.0 * 6.8e-06 * 0.8, T_SS_MAX = 750000.0 * 6.8e-06 * 100.0;

    double cr    = fmax(exp((double)rl[0]) + 1.0, 1.0 + 1e-4);
    double fb    = 1.0 / (1.0 + exp(-(double)fbl[0]));
    double slope = 1.0 - 1.0 / cr;

    double s_af = T_AF_MIN + (T_AF_MAX - T_AF_MIN) / (1.0 + exp(-(double)uaf[0]));
    double s_as = T_AS_MIN + (T_AS_MAX - T_AS_MIN) / (1.0 + exp(-(double)uas[0]));
    double s_sf = T_SF_MIN + (T_SF_MAX - T_SF_MIN) / (1.0 + exp(-(double)usf[0]));
    double s_ss = T_SS_MIN + (T_SS_MAX - T_SS_MIN) / (1.0 + exp(-(double)uss[0]));

    float a_af = (float)exp(-1.0 / (FS * s_af));
    float a_as = (float)exp(-1.0 / (FS * s_as));
    float a_sf = (float)exp(-1.0 / (FS * s_sf));
    float a_ss = (float)exp(-1.0 / (FS * s_ss));
    double q = 0.5 * slope * fb;

    pw[0]  = (float)(-0.5 * slope);
    pw[1]  = (float)(0.5 * slope * (double)cth[0]);
    pw[2]  = (float)(-q);
    pw[3]  = (float)(0.5 + q);
    pw[4]  = a_af;  pw[5] = a_as;  pw[6] = a_sf;  pw[7] = a_ss;
    pw[8]  = a_af * a_af;  pw[9]  = a_as * a_as;
    pw[10] = a_sf * a_sf;  pw[11] = a_ss * a_ss;
    pw[12] = (float)(-0.25 * slope);
}

// Pass 1: decimated diagonal chunk maps at K ES-nodes, SUB snapshots/node.
// (unchanged from round 8: 67us, VALU-throughput bound, proven accuracy)
__global__ __launch_bounds__(256) void ssl_map(
        const float* __restrict__ x, __half2* __restrict__ mp,
        const float* __restrict__ pw, int B)
{
    int tid = blockIdx.x * 256 + threadIdx.x;
    int k  = tid & (K - 1);
    int bc = tid >> 4;                       // b*NCM + c
    if (bc >= B * NCM) return;
    int c  = bc & (NCM - 1);
    int b  = bc >> 6;                        // NCM = 64

    const float nhs_h = pw[12], hst = pw[1], nq = pw[2], r = pw[3];
    const float d_af = pw[8], d_as = pw[9], d_sf = pw[10], d_ss = pw[11];

    float v0s = -STEP_ES * (float)k;
    float EF = v0s, ES = v0s, Y = EF + ES;
    const float4* __restrict__ xr = reinterpret_cast<const float4*>(x + (size_t)b * T_LEN);
    const int v0 = c * (CM >> 2);

    float4 buf[DPF];
    #pragma unroll
    for (int i = 0; i < DPF; ++i) buf[i] = xr[v0 + i];

    #pragma unroll 1
    for (int q8 = 0; q8 < SUB; ++q8) {
        const int s0 = v0 + q8 * (CF >> 2);
        for (int v = s0; v < s0 + (CF >> 2); v += DPF) {
            #pragma unroll
            for (int i = 0; i < DPF; ++i) {
                float4 xv = buf[i];
                int nxt = v + DPF + i;
                if (nxt < NV_ROW) buf[i] = xr[nxt];
#define DEC_STEP(X0, X1) { \
                float sx2 = fmaf(nhs_h, (X0), fmaf(nhs_h, (X1), hst)); \
                float u2  = fmaf(nq, Y, sx2); \
                float t2  = fminf(u2, 0.0f); \
                bool att  = sx2 < r * Y; \
                float af  = att ? d_af : d_sf; \
                float as2 = att ? d_as : d_ss; \
                EF = fmaf(af,  EF - t2, t2); \
                ES = fmaf(as2, ES - t2, t2); \
                Y  = EF + ES; }
                DEC_STEP(xv.x, xv.y)
                DEC_STEP(xv.z, xv.w)
#undef DEC_STEP
            }
        }
        mp[((size_t)bc * SUB + q8) * K + k] = __floats2half2_rn(EF, ES);
    }
}

// Pass 2: ONE kernel per row: compose0 (LDS) -> NIT x (jac -> affine scan) -> out.
__global__ __launch_bounds__(512) void ssl_row(
        const float* __restrict__ x, float* __restrict__ out,
        const __half2* __restrict__ mp, const float* __restrict__ pw, int B)
{
    __shared__ __align__(16) __half2 mp_s[MP_ROW];   // 32 KB (row's map table)
    __shared__ float2 bnd_s[NC];                     // 4 KB boundary states
    __shared__ float4 JA[NC], JB[NC];                // 8+8 KB scan ping-pong
    __shared__ float2 GA[NC], GB[NC];                // 4+4 KB

    const int b = blockIdx.x;                        // row
    const int t = threadIdx.x;                       // 0..511
    if (b >= B) return;

    const float nhs = pw[0], hst = pw[1], nq = pw[2], r = pw[3];
    const float a_af = pw[4], a_as = pw[5], a_sf = pw[6], a_ss = pw[7];

    const float4* __restrict__ xr = reinterpret_cast<const float4*>(x + (size_t)b * T_LEN);

    // ---- stage map table: MP_ROW/4 = 2048 float4 = 32 KB (FIXED: /4 not >>3) ----
    {
        const float4* src = reinterpret_cast<const float4*>(mp + (size_t)b * MP_ROW);
        float4* dst = reinterpret_cast<float4*>(mp_s);
        for (int i = t; i < MP_ROW / 4; i += 512)    // 4 iterations
            dst[i] = src[i];
    }
    __syncthreads();

    // ---- compose0: serial chain over 64 coarse chunks (thread 0, LDS reads) ----
    if (t == 0) {
        float EF = 0.0f, ES = 0.0f;
        for (int c = 0; c < NCM; ++c) {
            bnd_s[SUB * c] = make_float2(EF, ES);
            float tt = -ES * INV_STEP;
            int idx = (int)tt;
            idx = idx < 0 ? 0 : (idx > K - 2 ? K - 2 : idx);
            float u = tt - (float)idx;
            const __half2* m = &mp_s[c * SUB * K];
            float2 a0 = __half22float2(m[(SUB - 1) * K + idx]);
            float2 a1 = __half22float2(m[(SUB - 1) * K + idx + 1]);
            EF = a0.x + (a1.x - a0.x) * u;
            ES = a0.y + (a1.y - a0.y) * u;
        }
    }
    __syncthreads();
    // intermediate snapshots in parallel (entry ES of each coarse chunk known)
    if (t < NCM * (SUB - 1)) {
        int c = t / (SUB - 1);
        int q = t - c * (SUB - 1);
        float ES = bnd_s[SUB * c].y;
        float tt = -ES * INV_STEP;
        int idx = (int)tt;
        idx = idx < 0 ? 0 : (idx > K - 2 ? K - 2 : idx);
        float u = tt - (float)idx;
        const __half2* m = &mp_s[c * SUB * K];
        float2 a0 = __half22float2(m[q * K + idx]);
        float2 a1 = __half22float2(m[q * K + idx + 1]);
        bnd_s[SUB * c + 1 + q] = make_float2(a0.x + (a1.x - a0.x) * u,
                                             a0.y + (a1.y - a0.y) * u);
    }
    __syncthreads();

    // ---- Newton iterations: jac (1 chunk/thread) -> affine scan ----
    #pragma unroll 1
    for (int it = 0; it < NIT; ++it) {
        {
            const int c = t;                 // NC == blockDim == 512
            float2 s0 = bnd_s[c];
            float EF = s0.x, ES = s0.y, Y = EF + ES;
            float jFx = 1.0f, jFy = 0.0f, jSx = 0.0f, jSy = 1.0f;
            const int v0 = c * (CF >> 2), v1 = v0 + (CF >> 2);

            float4 buf[DPF];
            #pragma unroll
            for (int i = 0; i < DPF; ++i) buf[i] = xr[v0 + i];

            for (int v = v0; v < v1; v += DPF) {
                #pragma unroll
                for (int i = 0; i < DPF; ++i) {
                    float4 xv = buf[i];
                    int nxt = v + DPF + i;
                    if (nxt < NV_ROW) buf[i] = xr[nxt];
#define SSL_STEP_J(XV) { \
                    float sx2 = fmaf(nhs, (XV), hst); \
                    float u2  = fmaf(nq, Y, sx2); \
                    float t2  = fminf(u2, 0.0f); \
                    bool g2   = u2 < 0.0f; \
                    bool att  = sx2 < r * Y; \
                    float af  = att ? a_af : a_sf; \
                    float as2 = att ? a_as : a_ss; \
                    float jYx = jFx + jSx, jYy = jFy + jSy; \
                    float jtx = g2 ? nq * jYx : 0.0f; \
                    float jty = g2 ? nq * jYy : 0.0f; \
                    jFx = fmaf(af,  jFx - jtx, jtx); \
                    jFy = fmaf(af,  jFy - jty, jty); \
                    jSx = fmaf(as2, jSx - jtx, jtx); \
                    jSy = fmaf(as2, jSy - jty, jty); \
                    EF  = fmaf(af,  EF - t2, t2); \
                    ES  = fmaf(as2, ES - t2, t2); \
                    Y   = EF + ES; }
                    SSL_STEP_J(xv.x)
                    SSL_STEP_J(xv.y)
                    SSL_STEP_J(xv.z)
                    SSL_STEP_J(xv.w)
#undef SSL_STEP_J
                }
            }
            JA[c] = make_float4(jFx, jFy, jSx, jSy);
            GA[c] = make_float2(EF - (jFx * s0.x + jFy * s0.y),
                                ES - (jSx * s0.x + jSy * s0.y));
        }
        __syncthreads();

        // Hillis-Steele inclusive scan of affine maps (later ∘ earlier).
        float4* Js = JA; float2* Gs = GA;
        float4* Jd = JB; float2* Gd = GB;
        #pragma unroll 1
        for (int d = 1; d < NC; d <<= 1) {
            float4 J = Js[t];
            float2 g = Gs[t];
            if (t >= d) {
                float4 Je = Js[t - d];
                float2 ge = Gs[t - d];
                float4 Jn;
                Jn.x = J.x * Je.x + J.y * Je.z;
                Jn.y = J.x * Je.y + J.y * Je.w;
                Jn.z = J.z * Je.x + J.w * Je.z;
                Jn.w = J.z * Je.y + J.w * Je.w;
                float2 gn;
                gn.x = J.x * ge.x + J.y * ge.y + g.x;
                gn.y = J.z * ge.x + J.w * ge.y + g.y;
                J = Jn; g = gn;
            }
            Jd[t] = J; Gd[t] = g;
            __syncthreads();
            float4* tJ = Js; Js = Jd; Jd = tJ;
            float2* tG = Gs; Gs = Gd; Gd = tG;
        }
        // boundary states: s_0 = 0; s_c = (prefix up to c-1) applied to 0 = g
        bnd_s[t] = (t == 0) ? make_float2(0.0f, 0.0f) : Gs[t - 1];
        __syncthreads();
    }

    // ---- out: rerun each fine chunk from corrected state, store y ----
    {
        const int c = t;
        float2 s = bnd_s[c];
        float EF = s.x, ES = s.y, Y = EF + ES;
        float4* __restrict__ yr = reinterpret_cast<float4*>(out + (size_t)b * T_LEN);
        const int v0 = c * (CF >> 2), v1 = v0 + (CF >> 2);

        float4 buf[DPF];
        #pragma unroll
        for (int i = 0; i < DPF; ++i) buf[i] = xr[v0 + i];

        for (int v = v0; v < v1; v += DPF) {
            #pragma unroll
            for (int i = 0; i < DPF; ++i) {
                float4 xv = buf[i];
                int nxt = v + DPF + i;
                if (nxt < NV_ROW) buf[i] = xr[nxt];
                float4 yo;
#define SSL_STEP(XV, YOUT) { \
                float sx2 = fmaf(nhs, (XV), hst); \
                float u2  = fmaf(nq, Y, sx2); \
                float t2  = fminf(u2, 0.0f); \
                bool att  = sx2 < r * Y; \
                float af  = att ? a_af : a_sf; \
                float as2 = att ? a_as : a_ss; \
                EF = fmaf(af,  EF - t2, t2); \
                ES = fmaf(as2, ES - t2, t2); \
                Y  = EF + ES; \
                (YOUT) = Y; }
                SSL_STEP(xv.x, yo.x)
                SSL_STEP(xv.y, yo.y)
                SSL_STEP(xv.z, yo.z)
                SSL_STEP(xv.w, yo.w)
#undef SSL_STEP
                yr[v + i] = yo;
            }
        }
    }
}

extern "C" void kernel_launch(void* const* d_in, const int* in_sizes, int n_in,
                              void* d_out, int out_size, void* d_ws, size_t ws_size,
                              hipStream_t stream) {
    const float* x = (const float*)d_in[0];
    const int B = in_sizes[0] / T_LEN;   // 128

    // ws: mp (4 MB, 16B-aligned at base) | pw (16 floats)
    __half2* mp = (__half2*)d_ws;
    float*   pw = (float*)(mp + (size_t)B * MP_ROW);

    ssl_params_k<<<1, 1, 0, stream>>>(
        pw,
        (const float*)d_in[1], (const float*)d_in[2], (const float*)d_in[3],
        (const float*)d_in[4], (const float*)d_in[5], (const float*)d_in[6],
        (const float*)d_in[7]);

    int map_threads = B * NCM * K;       // 131072
    ssl_map<<<(map_threads + 255) / 256, 256, 0, stream>>>(x, mp, pw, B);

    ssl_row<<<B, 512, 0, stream>>>(x, (float*)d_out, mp, pw, B);
}